// Round 4
// baseline (9571.861 us; speedup 1.0000x reference)
//
#include <hip/hip_runtime.h>
#include <hip/hip_bf16.h>
#include <math.h>

// Problem constants
#define DM 1024
#define NH 16
#define DH 64
#define SEQ 2048
#define BATCH 4
#define MROWS (BATCH * SEQ)   // 8192

typedef __attribute__((ext_vector_type(4))) float f32x4;
typedef __attribute__((ext_vector_type(8))) short bf16x8;  // 8 bf16 in 4 VGPRs

static __device__ __forceinline__ float bf2f(__hip_bfloat16 v) { return __bfloat162float(v); }

// ---------------------------------------------------------------------------
// Dtype sniffer (FIXED discriminator). Look at the LOW 16 bits of each dword
// of x, interpreted as bf16:
//   fp32 N(0,1) data -> low bits are low mantissa bits ~ uniform -> random
//     exponent -> "insane" (outside [1e-8,1e4]) ~84% of the time.
//   bf16 data -> low half is itself a genuine bf16 sample of N(0,1) ->
//     insane ~0%.
// flag = 1 (bf16) iff insane count over 16384 dwords < 5000.
// ---------------------------------------------------------------------------
__global__ void sniff_kernel(const unsigned int* __restrict__ x, int* __restrict__ flag)
{
    const int tid = threadIdx.x;
    int bad = 0;
    for (int i = tid; i < 16384; i += 256) {
        unsigned int w = x[i];
        float h0 = __uint_as_float(w << 16);   // low 16 bits as bf16
        float a0 = fabsf(h0);
        if (!(h0 == 0.0f || (a0 > 1e-8f && a0 < 1e4f))) bad++;   // NaN counts bad
    }
    __shared__ int sb[256];
    sb[tid] = bad;
    __syncthreads();
    for (int s = 128; s > 0; s >>= 1) {
        if (tid < s) sb[tid] += sb[tid + s];
        __syncthreads();
    }
    if (tid == 0) flag[0] = (sb[0] < 5000) ? 1 : 0;
}

// ---------------------------------------------------------------------------
// Canonicalize a tensor to bf16 (copy if already bf16, downconvert if fp32).
// n multiple of 8. Reads exactly n ELEMENTS of the flagged dtype (in-bounds
// for both interpretations since in_sizes is the element count).
// ---------------------------------------------------------------------------
__global__ __launch_bounds__(256) void convert_kernel(
    const void* __restrict__ src, __hip_bfloat16* __restrict__ dst,
    const int* __restrict__ flag, int n)
{
    const int is_bf16 = *flag;   // uniform
    const int stride = gridDim.x * 256 * 8;
    for (int i = (blockIdx.x * 256 + threadIdx.x) * 8; i < n; i += stride) {
        if (is_bf16) {
            *(bf16x8*)&dst[i] = *(const bf16x8*)((const unsigned short*)src + i);
        } else {
            const float* s = (const float*)src;
            f32x4 v0 = *(const f32x4*)&s[i];
            f32x4 v1 = *(const f32x4*)&s[i + 4];
            bf16x8 o;
            #pragma unroll
            for (int t = 0; t < 4; ++t) {
                __hip_bfloat16 b0 = __float2bfloat16(v0[t]);
                __hip_bfloat16 b1 = __float2bfloat16(v1[t]);
                o[t]     = *(short*)&b0;
                o[t + 4] = *(short*)&b1;
            }
            *(bf16x8*)&dst[i] = o;
        }
    }
}

// ---------------------------------------------------------------------------
// Workspace-too-small sentinel: fill output with ~1e9 so the reported absmax
// unambiguously signals the condition.
// ---------------------------------------------------------------------------
__global__ void sentinel_kernel(unsigned short* __restrict__ out, int n)
{
    for (int i = blockIdx.x * 256 + threadIdx.x; i < n; i += gridDim.x * 256)
        out[i] = 0x4E6E;   // bf16 ~ 9.96e8
}

// ---------------------------------------------------------------------------
// GEMM: Y[m][n] = sum_k X[m][k] * W[n][k] + bias[n]   (bf16 in, fp32 accum)
// Block = 4 waves, 64x64 tile; wave = 32x32 (2x2 MFMA 16x16x32).
// Fragment layout (guide-verified m89/m91/m92):
//   A-frag: row = lane&15, k = 8*(lane>>4)+i
//   B-frag: col = lane&15, k = 8*(lane>>4)+i
//   C/D   : col = lane&15, row = (lane>>4)*4 + reg
// flagp == nullptr -> bf16 output; else fp32 output iff *flagp == 0.
// ---------------------------------------------------------------------------
__global__ __launch_bounds__(256) void gemm_bt(
    const __hip_bfloat16* __restrict__ X,
    const __hip_bfloat16* __restrict__ W,
    const __hip_bfloat16* __restrict__ bias,
    void* __restrict__ Y,
    const int* __restrict__ flagp)
{
    const int lane = threadIdx.x & 63;
    const int wave = threadIdx.x >> 6;
    const int wm = wave >> 1, wn = wave & 1;
    const int m0 = blockIdx.x * 64 + wm * 32;
    const int n0 = blockIdx.y * 64 + wn * 32;
    const int lr = lane & 15;
    const int lk = (lane >> 4) * 8;

    f32x4 acc[2][2] = {};
    for (int k0 = 0; k0 < DM; k0 += 32) {
        bf16x8 a0 = *(const bf16x8*)&X[(size_t)(m0 + lr) * DM + k0 + lk];
        bf16x8 a1 = *(const bf16x8*)&X[(size_t)(m0 + 16 + lr) * DM + k0 + lk];
        bf16x8 b0 = *(const bf16x8*)&W[(size_t)(n0 + lr) * DM + k0 + lk];
        bf16x8 b1 = *(const bf16x8*)&W[(size_t)(n0 + 16 + lr) * DM + k0 + lk];
        acc[0][0] = __builtin_amdgcn_mfma_f32_16x16x32_bf16(a0, b0, acc[0][0], 0, 0, 0);
        acc[0][1] = __builtin_amdgcn_mfma_f32_16x16x32_bf16(a0, b1, acc[0][1], 0, 0, 0);
        acc[1][0] = __builtin_amdgcn_mfma_f32_16x16x32_bf16(a1, b0, acc[1][0], 0, 0, 0);
        acc[1][1] = __builtin_amdgcn_mfma_f32_16x16x32_bf16(a1, b1, acc[1][1], 0, 0, 0);
    }

    const int fp32out = flagp ? (flagp[0] == 0) : 0;   // uniform
    const int orow = (lane >> 4) * 4;
    #pragma unroll
    for (int mi = 0; mi < 2; ++mi) {
        #pragma unroll
        for (int ni = 0; ni < 2; ++ni) {
            float bv = bf2f(bias[n0 + ni * 16 + lr]);
            #pragma unroll
            for (int r = 0; r < 4; ++r) {
                size_t off = (size_t)(m0 + mi * 16 + orow + r) * DM + n0 + ni * 16 + lr;
                float val = acc[mi][ni][r] + bv;
                if (fp32out) ((float*)Y)[off] = val;
                else         ((__hip_bfloat16*)Y)[off] = __float2bfloat16(val);
            }
        }
    }
}

// ---------------------------------------------------------------------------
// BISECTION attention: dead-simple scalar flash. One wave per q-row.
// Lane d (0..63) owns head-dim d. Per key: coalesced 64-lane K/V row loads,
// wave-reduce dot product, online softmax. Obviously correct; slow (~2.4ms).
// Ao may alias Qp: each wave reads only its own (row, head) Q region at
// start and writes the same region at end; all other regions disjoint.
// ---------------------------------------------------------------------------
__global__ __launch_bounds__(256) void attn_simple(
    const __hip_bfloat16* Qp,
    const __hip_bfloat16* __restrict__ Kp,
    const __hip_bfloat16* __restrict__ Vp,
    const int* __restrict__ mask,
    __hip_bfloat16* O)
{
    const int lane = threadIdx.x & 63;
    const int wave = threadIdx.x >> 6;
    const int row  = blockIdx.x * 4 + wave;   // 0..2047
    const int h    = blockIdx.y;
    const int b    = blockIdx.z;

    const size_t rbase = ((size_t)b * SEQ + row) * DM + h * DH;
    const float qv = bf2f(Qp[rbase + lane]);

    float m = -1e30f, l = 0.f, o = 0.f;
    const int nk = row + 1;   // causal
    for (int kk = 0; kk < nk; ++kk) {
        const size_t kbase = ((size_t)b * SEQ + kk) * DM + h * DH;
        float part = qv * bf2f(Kp[kbase + lane]);
        #pragma unroll
        for (int off = 32; off > 0; off >>= 1) part += __shfl_xor(part, off);
        float s = part * 0.125f;                     // 1/sqrt(64)
        if (mask[b * SEQ + kk] == 0) s = -1e30f;
        float mn = fmaxf(m, s);
        float alpha = __expf(m - mn);
        float p     = __expf(s - mn);
        float vd = bf2f(Vp[kbase + lane]);
        o = o * alpha + p * vd;
        l = l * alpha + p;
        m = mn;
    }
    O[rbase + lane] = __float2bfloat16(o / l);
}

// ---------------------------------------------------------------------------
extern "C" void kernel_launch(void* const* d_in, const int* in_sizes, int n_in,
                              void* d_out, int out_size, void* d_ws, size_t ws_size,
                              hipStream_t stream)
{
    const void* x_raw  = d_in[0];
    const int*  mk     = (const int*)d_in[1];
    const void* W_raw[4] = { d_in[2], d_in[4], d_in[6], d_in[8] };
    const void* b_raw[4] = { d_in[3], d_in[5], d_in[7], d_in[9] };

    const size_t SZ = (size_t)MROWS * DM;   // elements per [B*L][DM] buffer
    const size_t need = 256 + 2 * (SZ + 4 * (size_t)DM * DM + 4 * (size_t)DM + 3 * SZ);
    if (ws_size < need) {
        // Signal "workspace too small" via absmax ~1e9.
        sentinel_kernel<<<2048, 256, 0, stream>>>((unsigned short*)d_out, out_size);
        return;
    }

    char* base = (char*)d_ws;
    int* flag = (int*)base;
    __hip_bfloat16* xb = (__hip_bfloat16*)(base + 256);
    __hip_bfloat16* Wb[4];
    Wb[0] = xb + SZ;
    Wb[1] = Wb[0] + (size_t)DM * DM;
    Wb[2] = Wb[1] + (size_t)DM * DM;
    Wb[3] = Wb[2] + (size_t)DM * DM;
    __hip_bfloat16* bb[4];
    bb[0] = Wb[3] + (size_t)DM * DM;
    bb[1] = bb[0] + DM;
    bb[2] = bb[1] + DM;
    bb[3] = bb[2] + DM;
    __hip_bfloat16* Qp = bb[3] + DM;
    __hip_bfloat16* Kp = Qp + SZ;
    __hip_bfloat16* Vp = Kp + SZ;
    __hip_bfloat16* Ao = Qp;   // alias: safe per-region read-then-write ownership

    // 1) dtype sniff (flag: 1=bf16, 0=fp32); recomputed every launch
    sniff_kernel<<<1, 256, 0, stream>>>((const unsigned int*)x_raw, flag);

    // 2) canonicalize inputs to bf16
    convert_kernel<<<4096, 256, 0, stream>>>(x_raw, xb, flag, MROWS * DM);
    for (int t = 0; t < 4; ++t) {
        convert_kernel<<<512, 256, 0, stream>>>(W_raw[t], Wb[t], flag, DM * DM);
        convert_kernel<<<1, 256, 0, stream>>>(b_raw[t], bb[t], flag, DM);
    }

    // 3) projections (MFMA path under test)
    dim3 gblk(MROWS / 64, DM / 64, 1);
    gemm_bt<<<gblk, 256, 0, stream>>>(xb, Wb[0], bb[0], Qp, nullptr);
    gemm_bt<<<gblk, 256, 0, stream>>>(xb, Wb[1], bb[1], Kp, nullptr);
    gemm_bt<<<gblk, 256, 0, stream>>>(xb, Wb[2], bb[2], Vp, nullptr);

    // 4) attention: obviously-correct scalar flash (bisection reference)
    attn_simple<<<dim3(SEQ / 4, NH, BATCH), 256, 0, stream>>>(Qp, Kp, Vp, mk, Ao);

    // 5) output projection (fp32 out iff inputs were fp32)
    gemm_bt<<<gblk, 256, 0, stream>>>(Ao, Wb[3], bb[3], (void*)d_out, flag);
}

// Round 5
// 867.723 us; speedup vs baseline: 11.0310x; 11.0310x over previous
//
#include <hip/hip_runtime.h>
#include <hip/hip_bf16.h>
#include <math.h>

// Problem constants
#define DM 1024
#define NH 16
#define DH 64
#define SEQ 2048
#define BATCH 4
#define MROWS (BATCH * SEQ)   // 8192

typedef __attribute__((ext_vector_type(4))) float f32x4;
typedef __attribute__((ext_vector_type(8))) short bf16x8;  // 8 bf16 in 4 VGPRs

static __device__ __forceinline__ float bf2f(__hip_bfloat16 v) { return __bfloat162float(v); }

// ---------------------------------------------------------------------------
// Dtype sniffer (verified working in R4): low 16 bits of each dword as bf16.
// fp32 N(0,1) -> random exponent -> insane ~84%; bf16 -> insane ~0%.
// ---------------------------------------------------------------------------
__global__ void sniff_kernel(const unsigned int* __restrict__ x, int* __restrict__ flag)
{
    const int tid = threadIdx.x;
    int bad = 0;
    for (int i = tid; i < 16384; i += 256) {
        unsigned int w = x[i];
        float h0 = __uint_as_float(w << 16);
        float a0 = fabsf(h0);
        if (!(h0 == 0.0f || (a0 > 1e-8f && a0 < 1e4f))) bad++;
    }
    __shared__ int sb[256];
    sb[tid] = bad;
    __syncthreads();
    for (int s = 128; s > 0; s >>= 1) {
        if (tid < s) sb[tid] += sb[tid + s];
        __syncthreads();
    }
    if (tid == 0) flag[0] = (sb[0] < 5000) ? 1 : 0;
}

// ---------------------------------------------------------------------------
// Canonicalize to bf16 (copy if bf16, downconvert if fp32). n % 8 == 0.
// ---------------------------------------------------------------------------
__global__ __launch_bounds__(256) void convert_kernel(
    const void* __restrict__ src, __hip_bfloat16* __restrict__ dst,
    const int* __restrict__ flag, int n)
{
    const int is_bf16 = *flag;
    const int stride = gridDim.x * 256 * 8;
    for (int i = (blockIdx.x * 256 + threadIdx.x) * 8; i < n; i += stride) {
        if (is_bf16) {
            *(bf16x8*)&dst[i] = *(const bf16x8*)((const unsigned short*)src + i);
        } else {
            const float* s = (const float*)src;
            f32x4 v0 = *(const f32x4*)&s[i];
            f32x4 v1 = *(const f32x4*)&s[i + 4];
            bf16x8 o;
            #pragma unroll
            for (int t = 0; t < 4; ++t) {
                __hip_bfloat16 b0 = __float2bfloat16(v0[t]);
                __hip_bfloat16 b1 = __float2bfloat16(v1[t]);
                o[t]     = *(short*)&b0;
                o[t + 4] = *(short*)&b1;
            }
            *(bf16x8*)&dst[i] = o;
        }
    }
}

// ---------------------------------------------------------------------------
// Workspace-too-small sentinel (absmax ~1e9 signals the condition).
// ---------------------------------------------------------------------------
__global__ void sentinel_kernel(unsigned short* __restrict__ out, int n)
{
    for (int i = blockIdx.x * 256 + threadIdx.x; i < n; i += gridDim.x * 256)
        out[i] = 0x4E6E;   // bf16 ~ 9.96e8
}

// ---------------------------------------------------------------------------
// GEMM (R4-verified): Y[m][n] = sum_k X[m][k]*W[n][k] + bias[n].
// 64x64 block tile, 4 waves, 2x2 MFMA 16x16x32 per wave.
// ---------------------------------------------------------------------------
__global__ __launch_bounds__(256) void gemm_bt(
    const __hip_bfloat16* __restrict__ X,
    const __hip_bfloat16* __restrict__ W,
    const __hip_bfloat16* __restrict__ bias,
    void* __restrict__ Y,
    const int* __restrict__ flagp)
{
    const int lane = threadIdx.x & 63;
    const int wave = threadIdx.x >> 6;
    const int wm = wave >> 1, wn = wave & 1;
    const int m0 = blockIdx.x * 64 + wm * 32;
    const int n0 = blockIdx.y * 64 + wn * 32;
    const int lr = lane & 15;
    const int lk = (lane >> 4) * 8;

    f32x4 acc[2][2] = {};
    for (int k0 = 0; k0 < DM; k0 += 32) {
        bf16x8 a0 = *(const bf16x8*)&X[(size_t)(m0 + lr) * DM + k0 + lk];
        bf16x8 a1 = *(const bf16x8*)&X[(size_t)(m0 + 16 + lr) * DM + k0 + lk];
        bf16x8 b0 = *(const bf16x8*)&W[(size_t)(n0 + lr) * DM + k0 + lk];
        bf16x8 b1 = *(const bf16x8*)&W[(size_t)(n0 + 16 + lr) * DM + k0 + lk];
        acc[0][0] = __builtin_amdgcn_mfma_f32_16x16x32_bf16(a0, b0, acc[0][0], 0, 0, 0);
        acc[0][1] = __builtin_amdgcn_mfma_f32_16x16x32_bf16(a0, b1, acc[0][1], 0, 0, 0);
        acc[1][0] = __builtin_amdgcn_mfma_f32_16x16x32_bf16(a1, b0, acc[1][0], 0, 0, 0);
        acc[1][1] = __builtin_amdgcn_mfma_f32_16x16x32_bf16(a1, b1, acc[1][1], 0, 0, 0);
    }

    const int fp32out = flagp ? (flagp[0] == 0) : 0;
    const int orow = (lane >> 4) * 4;
    #pragma unroll
    for (int mi = 0; mi < 2; ++mi) {
        #pragma unroll
        for (int ni = 0; ni < 2; ++ni) {
            float bv = bf2f(bias[n0 + ni * 16 + lr]);
            #pragma unroll
            for (int r = 0; r < 4; ++r) {
                size_t off = (size_t)(m0 + mi * 16 + orow + r) * DM + n0 + ni * 16 + lr;
                float val = acc[mi][ni][r] + bv;
                if (fp32out) ((float*)Y)[off] = val;
                else         ((__hip_bfloat16*)Y)[off] = __float2bfloat16(val);
            }
        }
    }
}

// ---------------------------------------------------------------------------
// MFMA flash attention, minimal-risk structure: ONE WAVE PER BLOCK.
// Block (qt, h, b): 16 q-rows q0=qt*16. Key tiles of 32. No cross-wave
// sharing; V^T fragments gathered directly from global (L2-resident);
// P goes through a wave-private LDS tile to re-layout D -> A fragment.
// Fragment layouts identical to the R4-verified gemm_bt chain.
// O may alias Qp: block reads ONLY its own (rows, head-cols) region at
// start and writes exactly that region at end; regions disjoint across
// blocks, so order/scheduling independent.
// ---------------------------------------------------------------------------
__global__ __launch_bounds__(64) void attn_mfma(
    const __hip_bfloat16* Qp,
    const __hip_bfloat16* __restrict__ Kp,
    const __hip_bfloat16* __restrict__ Vp,
    const int* __restrict__ mask,
    __hip_bfloat16* O)
{
    const int lane = threadIdx.x;      // one wave
    const int qt = blockIdx.x;         // 0..127
    const int h  = blockIdx.y;
    const int b  = blockIdx.z;
    const int lr = lane & 15;
    const int g  = lane >> 4;          // 0..3
    const int lk = g * 8;
    const int q0 = qt * 16;

    __shared__ short Pl[16][40];       // wave-private P tile [qrow][key0..31]

    const size_t rowQ = ((size_t)b * SEQ + q0 + lr) * DM + h * DH;
    bf16x8 aq0 = *(const bf16x8*)&Qp[rowQ + lk];        // d = lk..lk+7
    bf16x8 aq1 = *(const bf16x8*)&Qp[rowQ + 32 + lk];   // d = 32+lk..

    f32x4 oacc[4] = {};
    float mrun[4], lrun[4];
    #pragma unroll
    for (int r = 0; r < 4; ++r) { mrun[r] = -1e30f; lrun[r] = 0.f; }

    const int nkb = (q0 + 47) / 32;    // tiles covering keys 0..q0+15
    for (int kb = 0; kb < nkb; ++kb) {
        const int kbase = kb * 32;

        // --- S = Q K^T, two 16-key subtiles (same MFMA chain as gemm_bt) ---
        f32x4 sacc[2];
        #pragma unroll
        for (int j = 0; j < 2; ++j) {
            const __hip_bfloat16* kptr =
                &Kp[((size_t)b * SEQ + kbase + j * 16 + lr) * DM + h * DH + lk];
            bf16x8 kf0 = *(const bf16x8*)kptr;
            bf16x8 kf1 = *(const bf16x8*)(kptr + 32);
            f32x4 c = {};
            c = __builtin_amdgcn_mfma_f32_16x16x32_bf16(aq0, kf0, c, 0, 0, 0);
            c = __builtin_amdgcn_mfma_f32_16x16x32_bf16(aq1, kf1, c, 0, 0, 0);
            sacc[j] = c;
        }

        // --- scale + causal/padding mask; per-row max ---
        float sv[2][4];
        float rmax[4] = {-1e30f, -1e30f, -1e30f, -1e30f};
        #pragma unroll
        for (int j = 0; j < 2; ++j) {
            int key = kbase + j * 16 + lr;
            int mv  = mask[b * SEQ + key];
            #pragma unroll
            for (int r = 0; r < 4; ++r) {
                int q = q0 + g * 4 + r;
                float s = sacc[j][r] * 0.125f;        // 1/sqrt(64)
                bool ok = (key <= q) && (mv != 0);
                sv[j][r] = ok ? s : -1e30f;
                rmax[r] = fmaxf(rmax[r], sv[j][r]);
            }
        }
        #pragma unroll
        for (int r = 0; r < 4; ++r) {                 // 16-lane-group reduce
            float v = rmax[r];
            v = fmaxf(v, __shfl_xor(v, 1));
            v = fmaxf(v, __shfl_xor(v, 2));
            v = fmaxf(v, __shfl_xor(v, 4));
            v = fmaxf(v, __shfl_xor(v, 8));
            rmax[r] = v;
        }

        float alpha[4];
        #pragma unroll
        for (int r = 0; r < 4; ++r) {
            float mn = fmaxf(mrun[r], rmax[r]);
            alpha[r] = __expf(mrun[r] - mn);
            mrun[r] = mn;
        }

        // --- P = exp(S - m): store bf16 to LDS, accumulate row sums ---
        float psum[4] = {0.f, 0.f, 0.f, 0.f};
        #pragma unroll
        for (int j = 0; j < 2; ++j) {
            #pragma unroll
            for (int r = 0; r < 4; ++r) {
                float p = __expf(sv[j][r] - mrun[r]);
                psum[r] += p;
                __hip_bfloat16 pb = __float2bfloat16(p);
                Pl[g * 4 + r][j * 16 + lr] = *(short*)&pb;
            }
        }
        #pragma unroll
        for (int r = 0; r < 4; ++r) {
            float v = psum[r];
            v += __shfl_xor(v, 1);
            v += __shfl_xor(v, 2);
            v += __shfl_xor(v, 4);
            v += __shfl_xor(v, 8);
            lrun[r] = lrun[r] * alpha[r] + v;
        }
        #pragma unroll
        for (int dt = 0; dt < 4; ++dt)
            #pragma unroll
            for (int r = 0; r < 4; ++r) oacc[dt][r] *= alpha[r];

        __syncthreads();   // 1-wave barrier: P writes -> P reads (cheap)

        // --- O += P V : A-frag from LDS, V^T B-frags gathered from global ---
        bf16x8 pa = *(const bf16x8*)&Pl[lr][lk];      // P[lr][8g..8g+7]
        const unsigned short* vbase =
            (const unsigned short*)&Vp[((size_t)b * SEQ + kbase + lk) * DM + h * DH];
        #pragma unroll
        for (int dt = 0; dt < 4; ++dt) {
            bf16x8 vb;
            #pragma unroll
            for (int t = 0; t < 8; ++t)
                vb[t] = (short)vbase[(size_t)t * DM + dt * 16 + lr];  // V[kbase+8g+t][dt*16+lr]
            oacc[dt] = __builtin_amdgcn_mfma_f32_16x16x32_bf16(pa, vb, oacc[dt], 0, 0, 0);
        }
        __syncthreads();   // P reads done before next iteration's writes
    }

    // --- epilogue: O / l ---
    #pragma unroll
    for (int r = 0; r < 4; ++r) {
        float inv = 1.0f / lrun[r];
        size_t rbase = ((size_t)b * SEQ + q0 + g * 4 + r) * DM + h * DH;
        #pragma unroll
        for (int dt = 0; dt < 4; ++dt)
            O[rbase + dt * 16 + lr] = __float2bfloat16(oacc[dt][r] * inv);
    }
}

// ---------------------------------------------------------------------------
extern "C" void kernel_launch(void* const* d_in, const int* in_sizes, int n_in,
                              void* d_out, int out_size, void* d_ws, size_t ws_size,
                              hipStream_t stream)
{
    const void* x_raw  = d_in[0];
    const int*  mk     = (const int*)d_in[1];
    const void* W_raw[4] = { d_in[2], d_in[4], d_in[6], d_in[8] };
    const void* b_raw[4] = { d_in[3], d_in[5], d_in[7], d_in[9] };

    const size_t SZ = (size_t)MROWS * DM;
    const size_t need = 256 + 2 * (SZ + 4 * (size_t)DM * DM + 4 * (size_t)DM + 3 * SZ);
    if (ws_size < need) {
        sentinel_kernel<<<2048, 256, 0, stream>>>((unsigned short*)d_out, out_size);
        return;
    }

    char* base = (char*)d_ws;
    int* flag = (int*)base;
    __hip_bfloat16* xb = (__hip_bfloat16*)(base + 256);
    __hip_bfloat16* Wb[4];
    Wb[0] = xb + SZ;
    Wb[1] = Wb[0] + (size_t)DM * DM;
    Wb[2] = Wb[1] + (size_t)DM * DM;
    Wb[3] = Wb[2] + (size_t)DM * DM;
    __hip_bfloat16* bb[4];
    bb[0] = Wb[3] + (size_t)DM * DM;
    bb[1] = bb[0] + DM;
    bb[2] = bb[1] + DM;
    bb[3] = bb[2] + DM;
    __hip_bfloat16* Qp = bb[3] + DM;
    __hip_bfloat16* Kp = Qp + SZ;
    __hip_bfloat16* Vp = Kp + SZ;
    __hip_bfloat16* Ao = Qp;   // alias: per-block read-own-then-write-own, disjoint

    sniff_kernel<<<1, 256, 0, stream>>>((const unsigned int*)x_raw, flag);

    convert_kernel<<<4096, 256, 0, stream>>>(x_raw, xb, flag, MROWS * DM);
    for (int t = 0; t < 4; ++t) {
        convert_kernel<<<512, 256, 0, stream>>>(W_raw[t], Wb[t], flag, DM * DM);
        convert_kernel<<<1, 256, 0, stream>>>(b_raw[t], bb[t], flag, DM);
    }

    dim3 gblk(MROWS / 64, DM / 64, 1);
    gemm_bt<<<gblk, 256, 0, stream>>>(xb, Wb[0], bb[0], Qp, nullptr);
    gemm_bt<<<gblk, 256, 0, stream>>>(xb, Wb[1], bb[1], Kp, nullptr);
    gemm_bt<<<gblk, 256, 0, stream>>>(xb, Wb[2], bb[2], Vp, nullptr);

    attn_mfma<<<dim3(SEQ / 16, NH, BATCH), 64, 0, stream>>>(Qp, Kp, Vp, mk, Ao);

    gemm_bt<<<gblk, 256, 0, stream>>>(Ao, Wb[3], bb[3], (void*)d_out, flag);
}

// Round 6
// 748.982 us; speedup vs baseline: 12.7798x; 1.1585x over previous
//
#include <hip/hip_runtime.h>
#include <hip/hip_bf16.h>
#include <math.h>

#define DM 1024
#define NH 16
#define DH 64
#define SEQ 2048
#define BATCH 4
#define MROWS (BATCH * SEQ)   // 8192

typedef __attribute__((ext_vector_type(4))) float f32x4;
typedef __attribute__((ext_vector_type(8))) short bf16x8;  // 8 bf16 in 4 VGPRs

static __device__ __forceinline__ float bf2f(__hip_bfloat16 v) { return __bfloat162float(v); }

// async global->LDS, 16B per lane; LDS dest = wave-uniform base + lane*16
__device__ __forceinline__ void gl_lds16(const void* g, void* l) {
    __builtin_amdgcn_global_load_lds(
        (const __attribute__((address_space(1))) unsigned int*)g,
        (__attribute__((address_space(3))) unsigned int*)l, 16, 0, 0);
}

// ---------------------------------------------------------------------------
// Dtype sniffer (R4-verified): low 16 bits of each dword as bf16.
// ---------------------------------------------------------------------------
__global__ void sniff_kernel(const unsigned int* __restrict__ x, int* __restrict__ flag)
{
    const int tid = threadIdx.x;
    int bad = 0;
    for (int i = tid; i < 16384; i += 256) {
        unsigned int w = x[i];
        float h0 = __uint_as_float(w << 16);
        float a0 = fabsf(h0);
        if (!(h0 == 0.0f || (a0 > 1e-8f && a0 < 1e4f))) bad++;
    }
    __shared__ int sb[256];
    sb[tid] = bad;
    __syncthreads();
    for (int s = 128; s > 0; s >>= 1) {
        if (tid < s) sb[tid] += sb[tid + s];
        __syncthreads();
    }
    if (tid == 0) flag[0] = (sb[0] < 5000) ? 1 : 0;
}

__device__ __forceinline__ void conv8(const void* src, __hip_bfloat16* dst,
                                      int i, int is_bf16)
{
    if (is_bf16) {
        *(bf16x8*)&dst[i] = *(const bf16x8*)((const unsigned short*)src + i);
    } else {
        const float* s = (const float*)src;
        f32x4 v0 = *(const f32x4*)&s[i];
        f32x4 v1 = *(const f32x4*)&s[i + 4];
        bf16x8 o;
        #pragma unroll
        for (int t = 0; t < 4; ++t) {
            __hip_bfloat16 b0 = __float2bfloat16(v0[t]);
            __hip_bfloat16 b1 = __float2bfloat16(v1[t]);
            o[t]     = *(short*)&b0;
            o[t + 4] = *(short*)&b1;
        }
        *(bf16x8*)&dst[i] = o;
    }
}

__global__ __launch_bounds__(256) void convert_kernel(
    const void* __restrict__ src, __hip_bfloat16* __restrict__ dst,
    const int* __restrict__ flag, int n)
{
    const int is_bf16 = *flag;
    const int stride = gridDim.x * 256 * 8;
    for (int i = (blockIdx.x * 256 + threadIdx.x) * 8; i < n; i += stride)
        conv8(src, dst, i, is_bf16);
}

// W0..3 -> dW (4 contiguous DM*DM), b0..3 -> db (4 contiguous DM). grid (513,4).
__global__ __launch_bounds__(256) void convertWb_kernel(
    const void* s0, const void* s1, const void* s2, const void* s3,
    const void* t0, const void* t1, const void* t2, const void* t3,
    __hip_bfloat16* __restrict__ dW, __hip_bfloat16* __restrict__ db,
    const int* __restrict__ flag)
{
    const int is_bf16 = *flag;
    const int t = blockIdx.y;
    const void* sW = (t == 0) ? s0 : (t == 1) ? s1 : (t == 2) ? s2 : s3;
    const void* sB = (t == 0) ? t0 : (t == 1) ? t1 : (t == 2) ? t2 : t3;
    if (blockIdx.x < 512) {
        int i = (blockIdx.x * 256 + threadIdx.x) * 8;
        conv8(sW, dW + (size_t)t * DM * DM, i, is_bf16);
    } else if (threadIdx.x < 128) {
        conv8(sB, db + (size_t)t * DM, threadIdx.x * 8, is_bf16);
    }
}

__global__ void sentinel_kernel(unsigned short* __restrict__ out, int n)
{
    for (int i = blockIdx.x * 256 + threadIdx.x; i < n; i += gridDim.x * 256)
        out[i] = 0x4E6E;   // bf16 ~ 9.96e8
}

// ---------------------------------------------------------------------------
// GEMM, m97-style: 128x128 tile, BK=32, global_load_lds w16 staging,
// 4 waves each 64x64 (4x4 MFMA 16x16x32). Y = X W^T + bias.
// ---------------------------------------------------------------------------
__global__ __launch_bounds__(256, 2) void gemm128(
    const __hip_bfloat16* __restrict__ X,
    const __hip_bfloat16* __restrict__ W,
    const __hip_bfloat16* __restrict__ bias,
    void* __restrict__ Y,
    const int* __restrict__ flagp)
{
    __shared__ short As[128 * 32];
    __shared__ short Bs[128 * 32];
    const int lane = threadIdx.x & 63;
    const int wave = threadIdx.x >> 6;
    const int wm = wave >> 1, wn = wave & 1;
    const int m0 = blockIdx.x * 128;
    const int n0 = blockIdx.y * 128;
    const int lr = lane & 15;
    const int lk = (lane >> 4) * 8;

    // staging: 512 chunks of 16B per tile; thread covers chunks c0, c0+256
    const int c0 = wave * 64 + lane;
    const int r0 = c0 >> 2,        q0c = (c0 & 3) * 8;
    const int r1 = (c0 + 256) >> 2, q1c = ((c0 + 256) & 3) * 8;
    short* As0 = &As[wave * 512];
    short* As1 = &As[2048 + wave * 512];
    short* Bs0 = &Bs[wave * 512];
    short* Bs1 = &Bs[2048 + wave * 512];

    f32x4 acc[4][4] = {};

    for (int k0 = 0; k0 < DM; k0 += 32) {
        __syncthreads();   // previous iteration's ds_reads complete
        gl_lds16(&X[(size_t)(m0 + r0) * DM + k0 + q0c], As0);
        gl_lds16(&X[(size_t)(m0 + r1) * DM + k0 + q1c], As1);
        gl_lds16(&W[(size_t)(n0 + r0) * DM + k0 + q0c], Bs0);
        gl_lds16(&W[(size_t)(n0 + r1) * DM + k0 + q1c], Bs1);
        __syncthreads();   // compiler drains vmcnt before s_barrier -> staged

        bf16x8 a[4], bfr[4];
        #pragma unroll
        for (int i = 0; i < 4; ++i) {
            a[i]   = *(const bf16x8*)&As[(wm * 64 + i * 16 + lr) * 32 + lk];
            bfr[i] = *(const bf16x8*)&Bs[(wn * 64 + i * 16 + lr) * 32 + lk];
        }
        #pragma unroll
        for (int i = 0; i < 4; ++i)
            #pragma unroll
            for (int j = 0; j < 4; ++j)
                acc[i][j] = __builtin_amdgcn_mfma_f32_16x16x32_bf16(a[i], bfr[j], acc[i][j], 0, 0, 0);
    }

    const int fp32out = flagp ? (flagp[0] == 0) : 0;
    const int og = (lane >> 4) * 4;
    #pragma unroll
    for (int i = 0; i < 4; ++i) {
        #pragma unroll
        for (int j = 0; j < 4; ++j) {
            float bv = bf2f(bias[n0 + wn * 64 + j * 16 + lr]);
            #pragma unroll
            for (int r = 0; r < 4; ++r) {
                size_t off = (size_t)(m0 + wm * 64 + i * 16 + og + r) * DM
                           + n0 + wn * 64 + j * 16 + lr;
                float val = acc[i][j][r] + bv;
                if (fp32out) ((float*)Y)[off] = val;
                else         ((__hip_bfloat16*)Y)[off] = __float2bfloat16(val);
            }
        }
    }
}

// ---------------------------------------------------------------------------
// V transpose: VT[((b*NH+h)*DH + d)*SEQ + key] = V[(b*SEQ+key)*DM + h*DH + d]
// LDS-tiled 64x64, coalesced in and out.
// ---------------------------------------------------------------------------
__global__ __launch_bounds__(256) void vtrans(
    const __hip_bfloat16* __restrict__ V, __hip_bfloat16* __restrict__ VT)
{
    __shared__ short T[64][72];
    const int kt = blockIdx.x;   // 64-key tile
    const int h  = blockIdx.y;
    const int b  = blockIdx.z;
    const int tid = threadIdx.x;

    #pragma unroll
    for (int i = 0; i < 2; ++i) {
        int c = i * 256 + tid;
        int key = c >> 3, d8 = (c & 7) * 8;
        bf16x8 v = *(const bf16x8*)&V[((size_t)b * SEQ + kt * 64 + key) * DM + h * DH + d8];
        *(bf16x8*)&T[key][d8] = v;
    }
    __syncthreads();
    #pragma unroll
    for (int i = 0; i < 2; ++i) {
        int c = i * 256 + tid;
        int d = c >> 3, k8 = (c & 7) * 8;
        bf16x8 o;
        #pragma unroll
        for (int t = 0; t < 8; ++t) o[t] = T[k8 + t][d];
        *(bf16x8*)&VT[((size_t)(b * NH + h) * DH + d) * SEQ + kt * 64 + k8] = o;
    }
}

// ---------------------------------------------------------------------------
// Flash attention: 4 waves/block, wave w owns q-rows qb*64+w*16..+15.
// KVBLK=64. K-frags and V^T-frags straight from global (L2-resident).
// Waves are independent (per-wave Pl slice); nkb uniform across waves so
// barriers are non-divergent (surplus fully-masked tiles give p=0 exactly).
// O aliases Qp: each block reads only its own (rows, head-cols) Q region at
// start and writes exactly that region at end.
// ---------------------------------------------------------------------------
__global__ __launch_bounds__(256) void attn4(
    const __hip_bfloat16* Qp,
    const __hip_bfloat16* __restrict__ Kp,
    const __hip_bfloat16* __restrict__ VT,   // [B*NH*DH][SEQ]
    const int* __restrict__ mask,
    __hip_bfloat16* O)
{
    const int qb = blockIdx.x;   // 0..31
    const int h  = blockIdx.y;
    const int b  = blockIdx.z;
    const int lane = threadIdx.x & 63;
    const int wave = threadIdx.x >> 6;
    const int lr = lane & 15;
    const int g  = lane >> 4;
    const int lk = g * 8;
    const int q0 = qb * 64 + wave * 16;

    __shared__ short Pl[4][16][72];   // per-wave P tile [qrow][key 0..63]

    const size_t rowQ = ((size_t)b * SEQ + q0 + lr) * DM + h * DH;
    bf16x8 aq0 = *(const bf16x8*)&Qp[rowQ + lk];
    bf16x8 aq1 = *(const bf16x8*)&Qp[rowQ + 32 + lk];

    const size_t vtb = (size_t)(b * NH + h) * DH;

    f32x4 oacc[4] = {};
    float mrun[4], lrun[4];
    #pragma unroll
    for (int r = 0; r < 4; ++r) { mrun[r] = -1e30f; lrun[r] = 0.f; }

    const int nkb = qb + 1;   // uniform across waves (causal upper bound)
    for (int kb = 0; kb < nkb; ++kb) {
        const int kbase = kb * 64;

        // --- S = Q K^T (4 key subtiles of 16) ---
        f32x4 sacc[4];
        #pragma unroll
        for (int j = 0; j < 4; ++j) {
            const __hip_bfloat16* kptr =
                &Kp[((size_t)b * SEQ + kbase + j * 16 + lr) * DM + h * DH + lk];
            bf16x8 kf0 = *(const bf16x8*)kptr;
            bf16x8 kf1 = *(const bf16x8*)(kptr + 32);
            f32x4 c = {};
            c = __builtin_amdgcn_mfma_f32_16x16x32_bf16(aq0, kf0, c, 0, 0, 0);
            c = __builtin_amdgcn_mfma_f32_16x16x32_bf16(aq1, kf1, c, 0, 0, 0);
            sacc[j] = c;
        }

        // --- scale + causal/padding mask; row max ---
        float sv[4][4];
        float rmax[4] = {-1e30f, -1e30f, -1e30f, -1e30f};
        #pragma unroll
        for (int j = 0; j < 4; ++j) {
            int key = kbase + j * 16 + lr;
            int mv  = mask[b * SEQ + key];
            #pragma unroll
            for (int r = 0; r < 4; ++r) {
                int q = q0 + g * 4 + r;
                float s = sacc[j][r] * 0.125f;   // 1/sqrt(64)
                bool ok = (key <= q) && (mv != 0);
                sv[j][r] = ok ? s : -1e30f;
                rmax[r] = fmaxf(rmax[r], sv[j][r]);
            }
        }
        #pragma unroll
        for (int r = 0; r < 4; ++r) {            // 16-lane-group reduce
            float v = rmax[r];
            v = fmaxf(v, __shfl_xor(v, 1));
            v = fmaxf(v, __shfl_xor(v, 2));
            v = fmaxf(v, __shfl_xor(v, 4));
            v = fmaxf(v, __shfl_xor(v, 8));
            rmax[r] = v;
        }

        float alpha[4];
        #pragma unroll
        for (int r = 0; r < 4; ++r) {
            float mn = fmaxf(mrun[r], rmax[r]);
            alpha[r] = __expf(mrun[r] - mn);
            mrun[r] = mn;
        }

        // --- P = exp(S - m) -> LDS bf16; row sums ---
        float psum[4] = {0.f, 0.f, 0.f, 0.f};
        #pragma unroll
        for (int j = 0; j < 4; ++j) {
            #pragma unroll
            for (int r = 0; r < 4; ++r) {
                float p = __expf(sv[j][r] - mrun[r]);
                psum[r] += p;
                __hip_bfloat16 pb = __float2bfloat16(p);
                Pl[wave][g * 4 + r][j * 16 + lr] = *(short*)&pb;
            }
        }
        #pragma unroll
        for (int r = 0; r < 4; ++r) {
            float v = psum[r];
            v += __shfl_xor(v, 1);
            v += __shfl_xor(v, 2);
            v += __shfl_xor(v, 4);
            v += __shfl_xor(v, 8);
            lrun[r] = lrun[r] * alpha[r] + v;
        }
        #pragma unroll
        for (int dt = 0; dt < 4; ++dt)
            #pragma unroll
            for (int r = 0; r < 4; ++r) oacc[dt][r] *= alpha[r];

        __syncthreads();   // Pl writes -> Pl reads

        // --- O += P V : A from LDS, B = V^T rows from global ---
        bf16x8 pa0 = *(const bf16x8*)&Pl[wave][lr][lk];
        bf16x8 pa1 = *(const bf16x8*)&Pl[wave][lr][32 + lk];
        #pragma unroll
        for (int dt = 0; dt < 4; ++dt) {
            const __hip_bfloat16* vrow = &VT[(vtb + dt * 16 + lr) * SEQ + kbase];
            bf16x8 vb0 = *(const bf16x8*)&vrow[lk];
            bf16x8 vb1 = *(const bf16x8*)&vrow[32 + lk];
            oacc[dt] = __builtin_amdgcn_mfma_f32_16x16x32_bf16(pa0, vb0, oacc[dt], 0, 0, 0);
            oacc[dt] = __builtin_amdgcn_mfma_f32_16x16x32_bf16(pa1, vb1, oacc[dt], 0, 0, 0);
        }
        __syncthreads();   // Pl reads done before next tile's writes
    }

    #pragma unroll
    for (int r = 0; r < 4; ++r) {
        float inv = 1.0f / lrun[r];
        size_t rbase = ((size_t)b * SEQ + q0 + g * 4 + r) * DM + h * DH;
        #pragma unroll
        for (int dt = 0; dt < 4; ++dt)
            O[rbase + dt * 16 + lr] = __float2bfloat16(oacc[dt][r] * inv);
    }
}

// ---------------------------------------------------------------------------
extern "C" void kernel_launch(void* const* d_in, const int* in_sizes, int n_in,
                              void* d_out, int out_size, void* d_ws, size_t ws_size,
                              hipStream_t stream)
{
    const void* x_raw  = d_in[0];
    const int*  mk     = (const int*)d_in[1];

    const size_t SZ = (size_t)MROWS * DM;
    const size_t need = 256 + 2 * (SZ + 4 * (size_t)DM * DM + 4 * (size_t)DM + 3 * SZ);
    if (ws_size < need) {
        sentinel_kernel<<<2048, 256, 0, stream>>>((unsigned short*)d_out, out_size);
        return;
    }

    char* base = (char*)d_ws;
    int* flag = (int*)base;
    __hip_bfloat16* xb = (__hip_bfloat16*)(base + 256);   // also VT after GEMMs
    __hip_bfloat16* Wb0 = xb + SZ;                        // 4 contiguous DM*DM
    __hip_bfloat16* bb0 = Wb0 + 4 * (size_t)DM * DM;      // 4 contiguous DM
    __hip_bfloat16* Qp = bb0 + 4 * (size_t)DM;
    __hip_bfloat16* Kp = Qp + SZ;
    __hip_bfloat16* Vp = Kp + SZ;
    __hip_bfloat16* VT = xb;    // reuse: xb dead after projection GEMMs
    __hip_bfloat16* Ao = Qp;    // alias: per-block read-own-then-write-own

    sniff_kernel<<<1, 256, 0, stream>>>((const unsigned int*)x_raw, flag);

    convert_kernel<<<4096, 256, 0, stream>>>(x_raw, xb, flag, MROWS * DM);
    convertWb_kernel<<<dim3(513, 4), 256, 0, stream>>>(
        d_in[2], d_in[4], d_in[6], d_in[8],
        d_in[3], d_in[5], d_in[7], d_in[9],
        Wb0, bb0, flag);

    dim3 gblk(MROWS / 128, DM / 128, 1);   // 64 x 8
    gemm128<<<gblk, 256, 0, stream>>>(xb, Wb0,                  bb0,          Qp, nullptr);
    gemm128<<<gblk, 256, 0, stream>>>(xb, Wb0 + (size_t)DM*DM,  bb0 + DM,     Kp, nullptr);
    gemm128<<<gblk, 256, 0, stream>>>(xb, Wb0 + 2*(size_t)DM*DM, bb0 + 2*DM,  Vp, nullptr);

    vtrans<<<dim3(SEQ / 64, NH, BATCH), 256, 0, stream>>>(Vp, VT);

    attn4<<<dim3(SEQ / 64, NH, BATCH), 256, 0, stream>>>(Qp, Kp, VT, mk, Ao);

    gemm128<<<gblk, 256, 0, stream>>>(Ao, Wb0 + 3*(size_t)DM*DM, bb0 + 3*DM, (void*)d_out, flag);
}

// Round 7
// 450.275 us; speedup vs baseline: 21.2578x; 1.6634x over previous
//
#include <hip/hip_runtime.h>
#include <hip/hip_bf16.h>
#include <math.h>

#define DM 1024
#define NH 16
#define DH 64
#define SEQ 2048
#define BATCH 4
#define MROWS (BATCH * SEQ)   // 8192

typedef __attribute__((ext_vector_type(4))) float f32x4;
typedef __attribute__((ext_vector_type(8))) short bf16x8;  // 8 bf16 in 4 VGPRs

static __device__ __forceinline__ float bf2f(__hip_bfloat16 v) { return __bfloat162float(v); }

// async global->LDS, 16B per lane; LDS dest = wave-uniform base + lane*16
__device__ __forceinline__ void gl_lds16(const void* g, void* l) {
    __builtin_amdgcn_global_load_lds(
        (const __attribute__((address_space(1))) unsigned int*)g,
        (__attribute__((address_space(3))) unsigned int*)l, 16, 0, 0);
}

// ---------------------------------------------------------------------------
// Dtype sniffer (R4-verified): low 16 bits of each dword as bf16.
// ---------------------------------------------------------------------------
__global__ void sniff_kernel(const unsigned int* __restrict__ x, int* __restrict__ flag)
{
    const int tid = threadIdx.x;
    int bad = 0;
    for (int i = tid; i < 16384; i += 256) {
        unsigned int w = x[i];
        float h0 = __uint_as_float(w << 16);
        float a0 = fabsf(h0);
        if (!(h0 == 0.0f || (a0 > 1e-8f && a0 < 1e4f))) bad++;
    }
    __shared__ int sb[256];
    sb[tid] = bad;
    __syncthreads();
    for (int s = 128; s > 0; s >>= 1) {
        if (tid < s) sb[tid] += sb[tid + s];
        __syncthreads();
    }
    if (tid == 0) flag[0] = (sb[0] < 5000) ? 1 : 0;
}

__device__ __forceinline__ void conv8(const void* src, __hip_bfloat16* dst,
                                      int i, int is_bf16)
{
    if (is_bf16) {
        *(bf16x8*)&dst[i] = *(const bf16x8*)((const unsigned short*)src + i);
    } else {
        const float* s = (const float*)src;
        f32x4 v0 = *(const f32x4*)&s[i];
        f32x4 v1 = *(const f32x4*)&s[i + 4];
        bf16x8 o;
        #pragma unroll
        for (int t = 0; t < 4; ++t) {
            __hip_bfloat16 b0 = __float2bfloat16(v0[t]);
            __hip_bfloat16 b1 = __float2bfloat16(v1[t]);
            o[t]     = *(short*)&b0;
            o[t + 4] = *(short*)&b1;
        }
        *(bf16x8*)&dst[i] = o;
    }
}

__global__ __launch_bounds__(256) void convert_kernel(
    const void* __restrict__ src, __hip_bfloat16* __restrict__ dst,
    const int* __restrict__ flag, int n)
{
    const int is_bf16 = *flag;
    const int stride = gridDim.x * 256 * 8;
    for (int i = (blockIdx.x * 256 + threadIdx.x) * 8; i < n; i += stride)
        conv8(src, dst, i, is_bf16);
}

// W0..3 -> dW (4 contiguous DM*DM), b0..3 -> db (4 contiguous DM). grid (513,4).
__global__ __launch_bounds__(256) void convertWb_kernel(
    const void* s0, const void* s1, const void* s2, const void* s3,
    const void* t0, const void* t1, const void* t2, const void* t3,
    __hip_bfloat16* __restrict__ dW, __hip_bfloat16* __restrict__ db,
    const int* __restrict__ flag)
{
    const int is_bf16 = *flag;
    const int t = blockIdx.y;
    const void* sW = (t == 0) ? s0 : (t == 1) ? s1 : (t == 2) ? s2 : s3;
    const void* sB = (t == 0) ? t0 : (t == 1) ? t1 : (t == 2) ? t2 : t3;
    if (blockIdx.x < 512) {
        int i = (blockIdx.x * 256 + threadIdx.x) * 8;
        conv8(sW, dW + (size_t)t * DM * DM, i, is_bf16);
    } else if (threadIdx.x < 128) {
        conv8(sB, db + (size_t)t * DM, threadIdx.x * 8, is_bf16);
    }
}

__global__ void sentinel_kernel(unsigned short* __restrict__ out, int n)
{
    for (int i = blockIdx.x * 256 + threadIdx.x; i < n; i += gridDim.x * 256)
        out[i] = 0x4E6E;   // bf16 ~ 9.96e8
}

// ---------------------------------------------------------------------------
// GEMM, m97-style (R6-verified): 128x128 tile, BK=32, global_load_lds w16,
// 4 waves each 64x64 (4x4 MFMA 16x16x32). Y = X W^T + bias.
// ---------------------------------------------------------------------------
__global__ __launch_bounds__(256, 2) void gemm128(
    const __hip_bfloat16* __restrict__ X,
    const __hip_bfloat16* __restrict__ W,
    const __hip_bfloat16* __restrict__ bias,
    void* __restrict__ Y,
    const int* __restrict__ flagp)
{
    __shared__ short As[128 * 32];
    __shared__ short Bs[128 * 32];
    const int lane = threadIdx.x & 63;
    const int wave = threadIdx.x >> 6;
    const int wm = wave >> 1, wn = wave & 1;
    const int m0 = blockIdx.x * 128;
    const int n0 = blockIdx.y * 128;
    const int lr = lane & 15;
    const int lk = (lane >> 4) * 8;

    const int c0 = wave * 64 + lane;
    const int r0 = c0 >> 2,         q0c = (c0 & 3) * 8;
    const int r1 = (c0 + 256) >> 2, q1c = ((c0 + 256) & 3) * 8;
    short* As0 = &As[wave * 512];
    short* As1 = &As[2048 + wave * 512];
    short* Bs0 = &Bs[wave * 512];
    short* Bs1 = &Bs[2048 + wave * 512];

    f32x4 acc[4][4] = {};

    for (int k0 = 0; k0 < DM; k0 += 32) {
        __syncthreads();
        gl_lds16(&X[(size_t)(m0 + r0) * DM + k0 + q0c], As0);
        gl_lds16(&X[(size_t)(m0 + r1) * DM + k0 + q1c], As1);
        gl_lds16(&W[(size_t)(n0 + r0) * DM + k0 + q0c], Bs0);
        gl_lds16(&W[(size_t)(n0 + r1) * DM + k0 + q1c], Bs1);
        __syncthreads();

        bf16x8 a[4], bfr[4];
        #pragma unroll
        for (int i = 0; i < 4; ++i) {
            a[i]   = *(const bf16x8*)&As[(wm * 64 + i * 16 + lr) * 32 + lk];
            bfr[i] = *(const bf16x8*)&Bs[(wn * 64 + i * 16 + lr) * 32 + lk];
        }
        #pragma unroll
        for (int i = 0; i < 4; ++i)
            #pragma unroll
            for (int j = 0; j < 4; ++j)
                acc[i][j] = __builtin_amdgcn_mfma_f32_16x16x32_bf16(a[i], bfr[j], acc[i][j], 0, 0, 0);
    }

    const int fp32out = flagp ? (flagp[0] == 0) : 0;
    const int og = (lane >> 4) * 4;
    #pragma unroll
    for (int i = 0; i < 4; ++i) {
        #pragma unroll
        for (int j = 0; j < 4; ++j) {
            float bv = bf2f(bias[n0 + wn * 64 + j * 16 + lr]);
            #pragma unroll
            for (int r = 0; r < 4; ++r) {
                size_t off = (size_t)(m0 + wm * 64 + i * 16 + og + r) * DM
                           + n0 + wn * 64 + j * 16 + lr;
                float val = acc[i][j][r] + bv;
                if (fp32out) ((float*)Y)[off] = val;
                else         ((__hip_bfloat16*)Y)[off] = __float2bfloat16(val);
            }
        }
    }
}

// ---------------------------------------------------------------------------
// V transpose (R6-verified): VT[((b*NH+h)*DH+d)*SEQ + key] = V[(b*SEQ+key)*DM + h*DH + d]
// ---------------------------------------------------------------------------
__global__ __launch_bounds__(256) void vtrans(
    const __hip_bfloat16* __restrict__ V, __hip_bfloat16* __restrict__ VT)
{
    __shared__ short T[64][72];
    const int kt = blockIdx.x;
    const int h  = blockIdx.y;
    const int b  = blockIdx.z;
    const int tid = threadIdx.x;

    #pragma unroll
    for (int i = 0; i < 2; ++i) {
        int c = i * 256 + tid;
        int key = c >> 3, d8 = (c & 7) * 8;
        bf16x8 v = *(const bf16x8*)&V[((size_t)b * SEQ + kt * 64 + key) * DM + h * DH + d8];
        *(bf16x8*)&T[key][d8] = v;
    }
    __syncthreads();
    #pragma unroll
    for (int i = 0; i < 2; ++i) {
        int c = i * 256 + tid;
        int d = c >> 3, k8 = (c & 7) * 8;
        bf16x8 o;
        #pragma unroll
        for (int t = 0; t < 8; ++t) o[t] = T[k8 + t][d];
        *(bf16x8*)&VT[((size_t)(b * NH + h) * DH + d) * SEQ + kt * 64 + k8] = o;
    }
}

// ---------------------------------------------------------------------------
// Flash attention, wave-independent + balanced pairing.
// Wave (blockIdx.x*4 + wave) owns 32-row q-tiles t0 and 63-t0 (work sums to
// ~33-34 K-tiles for every wave -> no tail). NO inter-wave barriers: Pl is
// per-wave; write->read ordering within the wave uses s_waitcnt lgkmcnt(0)
// (+ sched_barrier, rule #18). 2 slabs of 16 rows share each K/VT fragment.
// All fragment math is bit-identical to the R6-verified attn4.
// O aliases Qp: each (t,h,b) region is read once by its owner wave, then
// written by the same wave; regions disjoint across waves.
// ---------------------------------------------------------------------------
__global__ __launch_bounds__(256) void attn_pair(
    const __hip_bfloat16* Qp,
    const __hip_bfloat16* __restrict__ Kp,
    const __hip_bfloat16* __restrict__ VT,   // [B*NH*DH][SEQ]
    const int* __restrict__ mask,
    __hip_bfloat16* O)
{
    const int h = blockIdx.y, b = blockIdx.z;
    const int lane = threadIdx.x & 63;
    const int wave = threadIdx.x >> 6;
    const int lr = lane & 15, g = lane >> 4, lk = g * 8;
    const int t0 = blockIdx.x * 4 + wave;          // 0..31
    const size_t vtb = (size_t)(b * NH + h) * DH;

    __shared__ short Pl[4][2][16][72];             // per-wave, per-slab P

    #pragma unroll
    for (int half = 0; half < 2; ++half) {
        const int t = half ? (63 - t0) : t0;       // 32-row q-tile index
        const int q0 = t * 32;

        bf16x8 aq[2][2];
        #pragma unroll
        for (int s = 0; s < 2; ++s) {
            const size_t rq = ((size_t)b * SEQ + q0 + s * 16 + lr) * DM + h * DH;
            aq[s][0] = *(const bf16x8*)&Qp[rq + lk];
            aq[s][1] = *(const bf16x8*)&Qp[rq + 32 + lk];
        }

        f32x4 oacc[2][4] = {};
        float mrun[2][4], lrun[2][4];
        #pragma unroll
        for (int s = 0; s < 2; ++s)
            #pragma unroll
            for (int r = 0; r < 4; ++r) { mrun[s][r] = -1e30f; lrun[s][r] = 0.f; }

        const int nkb = t / 2 + 1;                 // covers keys 0..q0+31
        for (int kb = 0; kb < nkb; ++kb) {
            const int kbase = kb * 64;

            // --- S = Q K^T: K-frag loaded once, feeds both slabs ---
            f32x4 sacc[2][4];
            #pragma unroll
            for (int j = 0; j < 4; ++j) {
                const __hip_bfloat16* kptr =
                    &Kp[((size_t)b * SEQ + kbase + j * 16 + lr) * DM + h * DH + lk];
                bf16x8 kf0 = *(const bf16x8*)kptr;
                bf16x8 kf1 = *(const bf16x8*)(kptr + 32);
                #pragma unroll
                for (int s = 0; s < 2; ++s) {
                    f32x4 c = {};
                    c = __builtin_amdgcn_mfma_f32_16x16x32_bf16(aq[s][0], kf0, c, 0, 0, 0);
                    c = __builtin_amdgcn_mfma_f32_16x16x32_bf16(aq[s][1], kf1, c, 0, 0, 0);
                    sacc[s][j] = c;
                }
            }

            // --- mask + online softmax per slab (R6-verified math) ---
            #pragma unroll
            for (int s = 0; s < 2; ++s) {
                float sv[4][4];
                float rmax[4] = {-1e30f, -1e30f, -1e30f, -1e30f};
                #pragma unroll
                for (int j = 0; j < 4; ++j) {
                    int key = kbase + j * 16 + lr;
                    int mv  = mask[b * SEQ + key];
                    #pragma unroll
                    for (int r = 0; r < 4; ++r) {
                        int q = q0 + s * 16 + g * 4 + r;
                        float sval = sacc[s][j][r] * 0.125f;   // 1/sqrt(64)
                        bool ok = (key <= q) && (mv != 0);
                        sv[j][r] = ok ? sval : -1e30f;
                        rmax[r] = fmaxf(rmax[r], sv[j][r]);
                    }
                }
                #pragma unroll
                for (int r = 0; r < 4; ++r) {      // 16-lane-group reduce
                    float v = rmax[r];
                    v = fmaxf(v, __shfl_xor(v, 1));
                    v = fmaxf(v, __shfl_xor(v, 2));
                    v = fmaxf(v, __shfl_xor(v, 4));
                    v = fmaxf(v, __shfl_xor(v, 8));
                    rmax[r] = v;
                }
                float alpha[4];
                #pragma unroll
                for (int r = 0; r < 4; ++r) {
                    float mn = fmaxf(mrun[s][r], rmax[r]);
                    alpha[r] = __expf(mrun[s][r] - mn);
                    mrun[s][r] = mn;
                }
                float psum[4] = {0.f, 0.f, 0.f, 0.f};
                #pragma unroll
                for (int j = 0; j < 4; ++j) {
                    #pragma unroll
                    for (int r = 0; r < 4; ++r) {
                        float p = __expf(sv[j][r] - mrun[s][r]);
                        psum[r] += p;
                        __hip_bfloat16 pb = __float2bfloat16(p);
                        Pl[wave][s][g * 4 + r][j * 16 + lr] = *(short*)&pb;
                    }
                }
                #pragma unroll
                for (int r = 0; r < 4; ++r) {
                    float v = psum[r];
                    v += __shfl_xor(v, 1);
                    v += __shfl_xor(v, 2);
                    v += __shfl_xor(v, 4);
                    v += __shfl_xor(v, 8);
                    lrun[s][r] = lrun[s][r] * alpha[r] + v;
                }
                #pragma unroll
                for (int dt = 0; dt < 4; ++dt)
                    #pragma unroll
                    for (int r = 0; r < 4; ++r) oacc[s][dt][r] *= alpha[r];
            }

            // wave-local fence: Pl writes visible to this wave's reads
            asm volatile("s_waitcnt lgkmcnt(0)" ::: "memory");
            __builtin_amdgcn_sched_barrier(0);

            // --- O += P V : VT-frag loaded once, feeds both slabs ---
            bf16x8 pa[2][2];
            #pragma unroll
            for (int s = 0; s < 2; ++s) {
                pa[s][0] = *(const bf16x8*)&Pl[wave][s][lr][lk];
                pa[s][1] = *(const bf16x8*)&Pl[wave][s][lr][32 + lk];
            }
            #pragma unroll
            for (int dt = 0; dt < 4; ++dt) {
                const __hip_bfloat16* vrow = &VT[(vtb + dt * 16 + lr) * SEQ + kbase];
                bf16x8 vb0 = *(const bf16x8*)&vrow[lk];
                bf16x8 vb1 = *(const bf16x8*)&vrow[32 + lk];
                #pragma unroll
                for (int s = 0; s < 2; ++s) {
                    oacc[s][dt] = __builtin_amdgcn_mfma_f32_16x16x32_bf16(pa[s][0], vb0, oacc[s][dt], 0, 0, 0);
                    oacc[s][dt] = __builtin_amdgcn_mfma_f32_16x16x32_bf16(pa[s][1], vb1, oacc[s][dt], 0, 0, 0);
                }
            }
        }

        // --- epilogue: O / l ---
        #pragma unroll
        for (int s = 0; s < 2; ++s) {
            #pragma unroll
            for (int r = 0; r < 4; ++r) {
                float inv = 1.0f / lrun[s][r];
                size_t rbase = ((size_t)b * SEQ + q0 + s * 16 + g * 4 + r) * DM + h * DH;
                #pragma unroll
                for (int dt = 0; dt < 4; ++dt)
                    O[rbase + dt * 16 + lr] = __float2bfloat16(oacc[s][dt][r] * inv);
            }
        }
    }
}

// ---------------------------------------------------------------------------
extern "C" void kernel_launch(void* const* d_in, const int* in_sizes, int n_in,
                              void* d_out, int out_size, void* d_ws, size_t ws_size,
                              hipStream_t stream)
{
    const void* x_raw  = d_in[0];
    const int*  mk     = (const int*)d_in[1];

    const size_t SZ = (size_t)MROWS * DM;
    const size_t need = 256 + 2 * (SZ + 4 * (size_t)DM * DM + 4 * (size_t)DM + 3 * SZ);
    if (ws_size < need) {
        sentinel_kernel<<<2048, 256, 0, stream>>>((unsigned short*)d_out, out_size);
        return;
    }

    char* base = (char*)d_ws;
    int* flag = (int*)base;
    __hip_bfloat16* xb = (__hip_bfloat16*)(base + 256);   // also VT after GEMMs
    __hip_bfloat16* Wb0 = xb + SZ;                        // 4 contiguous DM*DM
    __hip_bfloat16* bb0 = Wb0 + 4 * (size_t)DM * DM;      // 4 contiguous DM
    __hip_bfloat16* Qp = bb0 + 4 * (size_t)DM;
    __hip_bfloat16* Kp = Qp + SZ;
    __hip_bfloat16* Vp = Kp + SZ;
    __hip_bfloat16* VT = xb;    // reuse: xb dead after projection GEMMs
    __hip_bfloat16* Ao = Qp;    // alias: per-wave read-own-then-write-own

    sniff_kernel<<<1, 256, 0, stream>>>((const unsigned int*)x_raw, flag);

    convert_kernel<<<4096, 256, 0, stream>>>(x_raw, xb, flag, MROWS * DM);
    convertWb_kernel<<<dim3(513, 4), 256, 0, stream>>>(
        d_in[2], d_in[4], d_in[6], d_in[8],
        d_in[3], d_in[5], d_in[7], d_in[9],
        Wb0, bb0, flag);

    dim3 gblk(MROWS / 128, DM / 128, 1);   // 64 x 8
    gemm128<<<gblk, 256, 0, stream>>>(xb, Wb0,                   bb0,         Qp, nullptr);
    gemm128<<<gblk, 256, 0, stream>>>(xb, Wb0 + (size_t)DM*DM,   bb0 + DM,    Kp, nullptr);
    gemm128<<<gblk, 256, 0, stream>>>(xb, Wb0 + 2*(size_t)DM*DM, bb0 + 2*DM,  Vp, nullptr);

    vtrans<<<dim3(SEQ / 64, NH, BATCH), 256, 0, stream>>>(Vp, VT);

    attn_pair<<<dim3(8, NH, BATCH), 256, 0, stream>>>(Qp, Kp, VT, mk, Ao);

    gemm128<<<gblk, 256, 0, stream>>>(Ao, Wb0 + 3*(size_t)DM*DM, bb0 + 3*DM, (void*)d_out, flag);
}